// Round 12
// baseline (93.354 us; speedup 1.0000x reference)
//
#include <hip/hip_runtime.h>
#include <hip/hip_bf16.h>

#define H_DIM   64
#define T_STEPS 128
#define B_TOT   4096
#define BB      16    // rows per block: TWO independent 8-row groups; grid 256 -> 1 block/CU
#define GR      8     // rows per group
#define SK      72    // padded row stride in halves for sX/sH
#define NTHREADS 512  // 8 waves; wave w owns cols w*8..w*8+7 for BOTH groups
#define XBATCH  8     // x prefetch depth; must divide T_STEPS

typedef _Float16 half8  __attribute__((ext_vector_type(8)));
typedef __attribute__((ext_vector_type(4))) float f32x4;

#if __has_builtin(__builtin_amdgcn_exp2f)
#define EXP2(x) __builtin_amdgcn_exp2f(x)
#else
#define EXP2(x) exp2f(x)
#endif

// Weights/biases pre-scaled by log2(e) (i,f,o) or 2*log2(e) (g): activations
// are raw exp2-domain. c lives in the 2*log2(e)-scaled domain.
__device__ __forceinline__ float sigmoid2(float xp) {      // xp = x*log2e
    return __builtin_amdgcn_rcpf(1.0f + EXP2(-xp));        // exact at +-inf
}
__device__ __forceinline__ float tanh2(float xp) {         // xp = 2*log2e*x
    return fmaf(-2.0f, __builtin_amdgcn_rcpf(EXP2(xp) + 1.0f), 1.0f);
}

// lane l <-> l^8 exchange within each 16-lane row: row_ror:8 DPP (VALU speed).
__device__ __forceinline__ float xor8_dpp(float v) {
    return __int_as_float(__builtin_amdgcn_mov_dpp(
        __float_as_int(v), 0x128 /*row_ror:8*/, 0xf, 0xf, false));
}

// Two independent 8-row LSTM groups (A,B) time-pipelined inside one block:
//   readA -> mfmaA -> readB -> mfmaB -> transA/publishA -> transB/publishB -> barrier
// B's MFMAs fill A's ds_read+MFMA latency; A's trans fills B's MFMA latency;
// one barrier retires BOTH groups' steps. Each group is exactly the R11 layout:
// 8 batch rows at M-rows {0,1,4,5,8,9,12,13}; 1 cell site per lane; gate
// exchange = 2 DPP xor-8 ops. Weights shared between groups.
__global__ __launch_bounds__(NTHREADS, 2) void lstm_fused(
    const int* __restrict__ inst, const float* __restrict__ embed,
    const float* __restrict__ Wih, const float* __restrict__ Whh,
    const float* __restrict__ bih, const float* __restrict__ bhh,
    float* __restrict__ out)
{
    __shared__ __align__(16) _Float16 sX[2][2][16][SK];   // [group][buf][mrow][k] 9.2 KB
    __shared__ __align__(16) _Float16 sH[2][2][16][SK];   // 9.2 KB
    __shared__ int sInst[BB * T_STEPS];                   // 8 KB

    const int tid  = (int)threadIdx.x;
    const int w    = tid >> 6;          // wave 0..7; stages batch rows w (A) and 8+w (B)
    const int l    = tid & 63;
    const int lrow = l & 15;            // A-row (m) / packed-n for B & C/D
    const int lk   = l >> 4;            // k-block; C/D rows are lk*4 + 0..3
    const bool losd = (lrow < 8);       // low gate-half of the packed tile
    const int col   = w * 8 + (lrow & 7);  // h-column of this lane's sites
    const int rstar = losd ? 0 : 1;     // row-slot this lane owns
    const int mrow  = lk * 4 + rstar;   // LDS/M-row of the site
    const int brA   = lk * 2 + rstar;   // group-A batch row of the site
    const int b0    = (int)blockIdx.x * BB;

    const float L2E     = 1.4426950408889634f;
    const float TWO_L2E = 2.8853900817779268f;

    // stage this block's instruction indices (16 rows x 128 steps)
    for (int i = tid; i < BB * T_STEPS; i += NTHREADS)
        sInst[i] = inst[b0 * T_STEPS + i];

    // zero all staging once: h0 = 0 AND the 8 permanently-garbage M-rows/group
    for (int i = tid; i < 2 * 2 * 16 * SK; i += NTHREADS) {
        ((_Float16*)sX)[i] = (_Float16)0.0f;
        ((_Float16*)sH)[i] = (_Float16)0.0f;
    }
    __syncthreads();

    // weight B-fragments (f16, exp2-prescaled), SHARED by both groups
    half8 wf[2][4];
    float bias[2];
#pragma unroll
    for (int q = 0; q < 2; ++q) {
        const int gate = q * 2 + (lrow >> 3);
        const float ws = (gate == 2) ? TWO_L2E : L2E;  // g feeds tanh(2x form)
        const int gcol = gate * 64 + col;              // W output row 0..255
        bias[q] = (bih[gcol] + bhh[gcol]) * ws;
#pragma unroll
        for (int kf = 0; kf < 4; ++kf) {
            const float* src = (kf < 2 ? Wih : Whh) + (long)gcol * H_DIM + (kf & 1) * 32 + lk * 8;
            half8 v;
#pragma unroll
            for (int jj = 0; jj < 8; ++jj) v[jj] = (_Float16)(src[jj] * ws);
            wf[q][kf] = v;
        }
    }

    // x staging: wave w owns batch row w (group A) / 8+w (group B), lane l = feature l
    const int xmw = (w >> 1) * 4 + (w & 1);
    {   // x(0) straight to LDS for both groups
        const int iA = sInst[w * T_STEPS + 0];
        sX[0][0][xmw][l] = (_Float16)embed[(long)iA * H_DIM + l];
        const int iB = sInst[(GR + w) * T_STEPS + 0];
        sX[1][0][xmw][l] = (_Float16)embed[(long)iB * H_DIM + l];
    }

    // register x-buffers (static indices only): entry (tt-1)&7 holds x(tt)
    float xbufA[XBATCH], xbufB[XBATCH];
#pragma unroll
    for (int j = 0; j < XBATCH; ++j) {
        xbufA[j] = embed[(long)sInst[w * T_STEPS + 1 + j] * H_DIM + l];
        xbufB[j] = embed[(long)sInst[(GR + w) * T_STEPS + 1 + j] * H_DIM + l];
    }
    __syncthreads();

    float cA = 0.f, hA = 0.f;   // group-A site (brA, col)
    float cB = 0.f, hB = 0.f;   // group-B site (8+brA, col)

    for (int tb = 0; tb < T_STEPS; tb += XBATCH) {
#pragma unroll
        for (int j = 0; j < XBATCH; ++j) {
            const int t   = tb + j;
            const int buf = j & 1;          // tb multiple of 8 -> static parity
            const int ob  = buf ^ 1;
            const bool pf = (t + 1 < T_STEPS);

            const float xcA = xbufA[j];     // x for step t+1 (loaded >=1 step ago)
            const float xcB = xbufB[j];

            // refill burst once per XBATCH steps: x(t+2 .. t+9), both groups
            if (j == XBATCH - 1 && pf) {
#pragma unroll
                for (int jj = 0; jj < XBATCH; ++jj) {
                    const int tt = t + 2 + jj;
                    if (tt < T_STEPS) {
                        xbufA[jj] = embed[(long)sInst[w * T_STEPS + tt] * H_DIM + l];
                        xbufB[jj] = embed[(long)sInst[(GR + w) * T_STEPS + tt] * H_DIM + l];
                    }
                }
            }

            // ---- group A: fragments + MFMA ----
            half8 aA0 = *reinterpret_cast<const half8*>(&sX[0][buf][lrow][lk * 8]);
            half8 aA1 = *reinterpret_cast<const half8*>(&sX[0][buf][lrow][32 + lk * 8]);
            half8 aA2 = *reinterpret_cast<const half8*>(&sH[0][buf][lrow][lk * 8]);
            half8 aA3 = *reinterpret_cast<const half8*>(&sH[0][buf][lrow][32 + lk * 8]);
            f32x4 accA[2];
#pragma unroll
            for (int q = 0; q < 2; ++q) {
                f32x4 a = {bias[q], bias[q], bias[q], bias[q]};
                a = __builtin_amdgcn_mfma_f32_16x16x32_f16(aA0, wf[q][0], a, 0, 0, 0);
                a = __builtin_amdgcn_mfma_f32_16x16x32_f16(aA1, wf[q][1], a, 0, 0, 0);
                a = __builtin_amdgcn_mfma_f32_16x16x32_f16(aA2, wf[q][2], a, 0, 0, 0);
                a = __builtin_amdgcn_mfma_f32_16x16x32_f16(aA3, wf[q][3], a, 0, 0, 0);
                accA[q] = a;
            }

            // ---- group B: fragments + MFMA (fills A's latency) ----
            half8 aB0 = *reinterpret_cast<const half8*>(&sX[1][buf][lrow][lk * 8]);
            half8 aB1 = *reinterpret_cast<const half8*>(&sX[1][buf][lrow][32 + lk * 8]);
            half8 aB2 = *reinterpret_cast<const half8*>(&sH[1][buf][lrow][lk * 8]);
            half8 aB3 = *reinterpret_cast<const half8*>(&sH[1][buf][lrow][32 + lk * 8]);
            f32x4 accB[2];
#pragma unroll
            for (int q = 0; q < 2; ++q) {
                f32x4 a = {bias[q], bias[q], bias[q], bias[q]};
                a = __builtin_amdgcn_mfma_f32_16x16x32_f16(aB0, wf[q][0], a, 0, 0, 0);
                a = __builtin_amdgcn_mfma_f32_16x16x32_f16(aB1, wf[q][1], a, 0, 0, 0);
                a = __builtin_amdgcn_mfma_f32_16x16x32_f16(aB2, wf[q][2], a, 0, 0, 0);
                a = __builtin_amdgcn_mfma_f32_16x16x32_f16(aB3, wf[q][3], a, 0, 0, 0);
                accB[q] = a;
            }

            // ---- group A: exchange + cell update + publish ----
            {
                const float r0 = xor8_dpp(losd ? accA[0][1] : accA[0][0]);
                const float r1 = xor8_dpp(losd ? accA[1][1] : accA[1][0]);
                const float vi = losd ? accA[0][0] : r0;
                const float vf = losd ? r0         : accA[0][1];
                const float vg = losd ? accA[1][0] : r1;
                const float vo = losd ? r1         : accA[1][1];
                const float iv = sigmoid2(vi);
                const float fv = sigmoid2(vf);
                const float gv = tanh2(vg);
                const float ov = sigmoid2(vo);
                const float cs = fmaf(fv, cA, iv * (gv * TWO_L2E));
                cA = cs;
                hA = ov * tanh2(cs);
                if (pf) {
                    sH[0][ob][mrow][col] = (_Float16)hA;
                    sX[0][ob][xmw][l]    = (_Float16)xcA;
                }
            }

            // ---- group B: exchange + cell update + publish ----
            {
                const float r0 = xor8_dpp(losd ? accB[0][1] : accB[0][0]);
                const float r1 = xor8_dpp(losd ? accB[1][1] : accB[1][0]);
                const float vi = losd ? accB[0][0] : r0;
                const float vf = losd ? r0         : accB[0][1];
                const float vg = losd ? accB[1][0] : r1;
                const float vo = losd ? r1         : accB[1][1];
                const float iv = sigmoid2(vi);
                const float fv = sigmoid2(vf);
                const float gv = tanh2(vg);
                const float ov = sigmoid2(vo);
                const float cs = fmaf(fv, cB, iv * (gv * TWO_L2E));
                cB = cs;
                hB = ov * tanh2(cs);
                if (pf) {
                    sH[1][ob][mrow][col] = (_Float16)hB;
                    sX[1][ob][xmw][l]    = (_Float16)xcB;
                }
            }

            __syncthreads();   // one barrier retires BOTH groups' steps
        }
    }

    // final h (f32) -> out[B][H]; one element per lane per group
    out[(long)(b0 + brA) * H_DIM + col]      = hA;
    out[(long)(b0 + GR + brA) * H_DIM + col] = hB;
}

extern "C" void kernel_launch(void* const* d_in, const int* in_sizes, int n_in,
                              void* d_out, int out_size, void* d_ws, size_t ws_size,
                              hipStream_t stream) {
    const int*   inst  = (const int*)  d_in[0];
    const float* embed = (const float*)d_in[1];
    const float* Wih   = (const float*)d_in[2];
    const float* Whh   = (const float*)d_in[3];
    const float* bih   = (const float*)d_in[4];
    const float* bhh   = (const float*)d_in[5];
    float* out = (float*)d_out;

    lstm_fused<<<B_TOT / BB, NTHREADS, 0, stream>>>(inst, embed, Wih, Whh, bih, bhh, out);
}